// Round 8
// baseline (289.519 us; speedup 1.0000x reference)
//
#include <hip/hip_runtime.h>
#include <hip/hip_bf16.h>

// MetaNetImageEncoder on MI355X — round 11.
// Post-mortem r10: prediction held (333->285.2, best). gemm_pool frozen at
// 80.2-80.4us (structural floor; 6 schedule variants all flat). Tail ~125us.
// r11: fuse gemm2#2 + combine -> k_gemm2c: grid (12 n-tiles x 4 K-splits)=48
// blocks; per block stage A k-tile ONCE, loop 9 mats over it (reg-pipelined
// B, 1 barrier/mat), acc[9][4] in VGPRs, coefs-weighted combine in epilogue
// -> Yp[4]. k_sum4 adds partials + b2 + c*db2. Kills Y roundtrip, old
// combine's 10-load/elem, and 12.7MB redundant A staging of the 108-block
// gemm2#2. Everything else byte-identical to r10.
//
// MFMA 16x16x32 bf16 layouts (learn_hip m89):
//   A-frag: A[m=lane&15][k=(lane>>4)*8+j], B-frag: B[k=(lane>>4)*8+j][n=lane&15]
//   C/D:    col=lane&15, row=(lane>>4)*4+reg

typedef __bf16 bf16x8 __attribute__((ext_vector_type(8)));
typedef float f32x4 __attribute__((ext_vector_type(4)));
typedef __hip_bfloat16 bf16;

struct alignas(16) BF8 { bf16 h[8]; };

constexpr int BATCH = 64;
constexpr int NP    = 196;
constexpr int NPAD  = 256;
constexpr int DIM   = 768;
constexpr int NT    = 8;
constexpr size_t MSZ = (size_t)DIM * DIM;

__device__ __forceinline__ void async_cp16(const void* g, void* l) {
  __builtin_amdgcn_global_load_lds(
      (const __attribute__((address_space(1))) uint32_t*)g,
      (__attribute__((address_space(3))) uint32_t*)l, 16, 0, 0);
}

// ---------------- K1: fused patchify(+cast, pad) and weight transpose(+cast) ----------------
constexpr int PREP_PATCH_BLOCKS = (BATCH * NPAD * (DIM / 4)) / 256;   // 12288
constexpr int PREP_TRANS_BLOCKS = 24 * 24 * 18;                       // 10368

__global__ void k_prep(const float* __restrict__ x, bf16* __restrict__ A,
                       const float* __restrict__ W1, const float* __restrict__ dW1,
                       const float* __restrict__ W2, const float* __restrict__ dW2,
                       bf16* __restrict__ WT) {
  __shared__ float tile[32][33];
  int blk = blockIdx.x;
  int tid = threadIdx.x;
  if (blk < PREP_PATCH_BLOCKS) {
    int idx  = blk * 256 + tid;
    int col4 = idx % (DIM / 4);
    int row  = idx / (DIM / 4);
    int d = col4 * 4;
    int b = row >> 8;
    int n = row & 255;
    bf16 tmp[4];
    if (n < NP) {
      int hp = n / 14, wp = n % 14;
      int c  = d >> 8;
      int rr = d & 255;
      int i = rr >> 4, j = rr & 15;
      const float* src = x + ((((size_t)b * 3 + c) * 224 + hp * 16 + i) * 224 + wp * 16 + j);
      float4 f = *(const float4*)src;
      tmp[0] = __float2bfloat16(f.x);
      tmp[1] = __float2bfloat16(f.y);
      tmp[2] = __float2bfloat16(f.z);
      tmp[3] = __float2bfloat16(f.w);
    } else {
      tmp[0] = tmp[1] = tmp[2] = tmp[3] = __float2bfloat16(0.0f);
    }
    *(ushort4*)(A + (size_t)row * DIM + d) = *(ushort4*)tmp;
  } else {
    int tb  = blk - PREP_PATCH_BLOCKS;
    int mat = tb / 576;
    int rem = tb % 576;
    int n0 = (rem % 24) * 32;
    int k0 = (rem / 24) * 32;
    const float* src;
    if      (mat == 0) src = W1;
    else if (mat <= 8) src = dW1 + (size_t)(mat - 1) * MSZ;
    else if (mat == 9) src = W2;
    else               src = dW2 + (size_t)(mat - 10) * MSZ;
    int tx = tid & 31, ty = tid >> 5;
#pragma unroll
    for (int r = ty; r < 32; r += 8)
      tile[r][tx] = src[(size_t)(k0 + r) * DIM + n0 + tx];
    __syncthreads();
    bf16* dst = WT + (size_t)mat * MSZ;
#pragma unroll
    for (int r = ty; r < 32; r += 8)
      dst[(size_t)(n0 + r) * DIM + k0 + tx] = __float2bfloat16(tile[tx][r]);
  }
}

// ---------------- K3: per-sample GEMM (+inline mix) + relu + masked column-mean --------------
// [r8/r10-measured body: 78.4-80.4us, 0 bank conflicts, WRITE 192KB — FROZEN]

#define WAITVM(N) asm volatile("s_waitcnt vmcnt(" #N ")" ::: "memory")

template<int MIX>
__global__ __launch_bounds__(256, 3)
void k_gemm_pool(const bf16* __restrict__ A,    // [64*256, 768]
                 const bf16* __restrict__ WT,   // mats 0..8 = W1T, dW1T[8]
                 const float* __restrict__ b1,
                 const float* __restrict__ db1,
                 const float* __restrict__ coefs,  // [64][8] (MIX only)
                 float* __restrict__ pooled) {     // f32 [64][768]
  __shared__ uint4 AslU[3][896];   // 224 rows x 4 granules x 16B, x3 bufs = 42KB
  __shared__ uint4 BslU[2][256];   //  64 rows x 4 granules x 16B, x2 bufs =  8KB

  int b  = blockIdx.x;
  int n0 = blockIdx.y * 64;
  int tid = threadIdx.x;
  int wave = tid >> 6, lane = tid & 63;
  int quad = lane >> 4, l16 = lane & 15;

  float cr[NT];
  if (MIX) {
#pragma unroll
    for (int t = 0; t < NT; t++) cr[t] = coefs[b * NT + t];
  }

  const bf16* Ag = A + (size_t)b * NPAD * DIM;
  f32x4 acc[4][4] = {};

  int gbase = (wave < 2) ? wave * 256 : 512 + (wave - 2) * 192;
  int gcnt  = (wave < 2) ? 4 : 3;
  int aoff[4];
#pragma unroll
  for (int i = 0; i < 4; i++) {
    int s = gbase + i * 64 + lane;
    int p = s >> 3, u = (s & 7) ^ (p & 7);
    int r = 2 * p + (u >> 2), c = u & 3;
    aoff[i] = r * DIM + c * 8;
  }
  auto stage_a = [&](int buf, int kt) {
    const bf16* Ak = Ag + kt * 32;
#pragma unroll
    for (int i = 0; i < 4; i++) {
      if (i < gcnt)
        async_cp16(Ak + aoff[i], (void*)&AslU[buf][gbase + i * 64]);
    }
  };

  int bp = tid >> 3, bu = (tid & 7) ^ (bp & 7);
  int brow_st = 2 * bp + (bu >> 2), bcol_st = bu & 3;
  const bf16* Wrow = WT + (size_t)(n0 + brow_st) * DIM + bcol_st * 8;

  BF8 wreg[MIX ? 9 : 1];
  auto breg_load = [&](int kt) {
    const bf16* p0 = Wrow + kt * 32;
    wreg[0] = *(const BF8*)p0;
    if (MIX) {
#pragma unroll
      for (int t = 0; t < NT; t++)
        wreg[1 + t] = *(const BF8*)(p0 + (size_t)(1 + t) * MSZ);
    }
  };
  auto breg_write = [&](int buf) {
    if (MIX) {
      float m[8];
#pragma unroll
      for (int j = 0; j < 8; j++) m[j] = __bfloat162float(wreg[0].h[j]);
#pragma unroll
      for (int t = 0; t < NT; t++) {
        float cc = cr[t];
#pragma unroll
        for (int j = 0; j < 8; j++) m[j] += cc * __bfloat162float(wreg[1 + t].h[j]);
      }
      BF8 o;
#pragma unroll
      for (int j = 0; j < 8; j++) o.h[j] = __float2bfloat16(m[j]);
      BslU[buf][tid] = *(uint4*)&o;
    } else {
      BslU[buf][tid] = *(uint4*)&wreg[0];
    }
  };

  auto gslot = [&](int row, int kq) {
    return (size_t)((row >> 1) * 8 + ((4 * (row & 1) + kq) ^ ((row >> 1) & 7)));
  };

  stage_a(0, 0);
  stage_a(1, 1);
  breg_load(0);
  WAITVM(0);
  __builtin_amdgcn_sched_barrier(0);
  breg_write(0);
  asm volatile("s_waitcnt lgkmcnt(0)" ::: "memory");

  int bufA = 0, stgA = 2, bufB = 0;
  for (int kt = 0; kt < 24; kt++) {
    __builtin_amdgcn_s_barrier();
    if (kt < 23) breg_load(kt + 1);
    __builtin_amdgcn_sched_barrier(0);
    if (kt < 22) stage_a(stgA, kt + 2);
    __builtin_amdgcn_sched_barrier(0);
    const bf16* As = (const bf16*)AslU[bufA];
    const bf16* Bs = (const bf16*)BslU[bufB];
    bf16x8 bfr[4];
#pragma unroll
    for (int nf = 0; nf < 4; nf++) {
      int brow = nf * 16 + l16;
      bfr[nf] = *(const bf16x8*)(Bs + gslot(brow, quad) * 8);
    }
    __builtin_amdgcn_s_setprio(1);
#pragma unroll
    for (int mf = 0; mf < 4; mf++) {
      if (wave * 64 + mf * 16 < 224) {
        int arow = wave * 64 + mf * 16 + l16;
        bf16x8 af = *(const bf16x8*)(As + gslot(arow, quad) * 8);
#pragma unroll
        for (int nf = 0; nf < 4; nf++)
          acc[mf][nf] = __builtin_amdgcn_mfma_f32_16x16x32_bf16(af, bfr[nf], acc[mf][nf], 0, 0, 0);
      }
    }
    __builtin_amdgcn_s_setprio(0);
    if (kt < 22) {
      if (wave < 2) WAITVM(4); else WAITVM(3);
    } else if (kt < 23) {
      WAITVM(0);
    }
    __builtin_amdgcn_sched_barrier(0);
    if (kt < 23) {
      breg_write(bufB ^ 1);
      asm volatile("s_waitcnt lgkmcnt(0)" ::: "memory");
    }
    bufA = (bufA == 2) ? 0 : bufA + 1;
    stgA = (stgA == 2) ? 0 : stgA + 1;
    bufB ^= 1;
  }

  float* red = (float*)&BslU[0][0];
  int m0 = wave * 64;
  float colsum[4];
#pragma unroll
  for (int nf = 0; nf < 4; nf++) {
    int col = n0 + nf * 16 + l16;
    float bias = b1[col];
    if (MIX) {
#pragma unroll
      for (int t = 0; t < NT; t++) bias += cr[t] * db1[t * DIM + col];
    }
    float s = 0.0f;
#pragma unroll
    for (int mf = 0; mf < 4; mf++) {
      int rbase = m0 + mf * 16 + quad * 4;
#pragma unroll
      for (int r = 0; r < 4; r++) {
        if (rbase + r < NP) s += fmaxf(acc[mf][nf][r] + bias, 0.0f);
      }
    }
    s += __shfl_xor(s, 16, 64);
    s += __shfl_xor(s, 32, 64);
    colsum[nf] = s;
  }
  if (lane < 16) {
#pragma unroll
    for (int nf = 0; nf < 4; nf++) red[wave * 64 + nf * 16 + lane] = colsum[nf];
  }
  __syncthreads();
  if (tid < 64) {
    float s = red[tid] + red[64 + tid] + red[128 + tid] + red[192 + tid];
    pooled[(size_t)b * DIM + n0 + tid] = s * (1.0f / 196.0f);
  }
}

// ---------------- K5a: base partials, K-split x4: basep[kz] = Af[:,kz*192:+192] @ W2T[kz] ----
__global__ __launch_bounds__(256, 2)
void k_gemm2_ksplit(const float* __restrict__ Af,    // [64][768] f32 (pooledA)
                    const bf16* __restrict__ WT,     // mat 9 = W2T
                    float* __restrict__ basep) {     // [4][64][768]
  __shared__ uint4 AslU[64 * 8];
  __shared__ uint4 BslU[64 * 8];
  int n0  = blockIdx.x * 64;
  int kz  = blockIdx.y;
  int tid = threadIdx.x, wave = tid >> 6, lane = tid & 63;
  int quad = lane >> 4, l16 = lane & 15;
  f32x4 acc[4] = {};
  const bf16* Wm = WT + (size_t)9 * MSZ;
  for (int k0 = kz * 192; k0 < kz * 192 + 192; k0 += 64) {
#pragma unroll
    for (int i = 0; i < 2; i++) {
      int g = tid + i * 256;
      int r = g >> 3, c = g & 7;
      const float* src = Af + (size_t)r * DIM + k0 + c * 8;
      float4 xa = ((const float4*)src)[0];
      float4 xb = ((const float4*)src)[1];
      BF8 o;
      o.h[0] = __float2bfloat16(xa.x); o.h[1] = __float2bfloat16(xa.y);
      o.h[2] = __float2bfloat16(xa.z); o.h[3] = __float2bfloat16(xa.w);
      o.h[4] = __float2bfloat16(xb.x); o.h[5] = __float2bfloat16(xb.y);
      o.h[6] = __float2bfloat16(xb.z); o.h[7] = __float2bfloat16(xb.w);
      AslU[r * 8 + (c ^ (r & 7))] = *(uint4*)&o;
      BslU[r * 8 + (c ^ (r & 7))] = *(const uint4*)(Wm + (size_t)(n0 + r) * DIM + k0 + c * 8);
    }
    __syncthreads();
    const bf16* As = (const bf16*)AslU;
    const bf16* Bs = (const bf16*)BslU;
#pragma unroll
    for (int ks = 0; ks < 2; ks++) {
      int brow = wave * 16 + l16;
      bf16x8 bfr = *(const bf16x8*)(Bs + (size_t)(brow * 8 + ((ks * 4 + quad) ^ (brow & 7))) * 8);
#pragma unroll
      for (int mf = 0; mf < 4; mf++) {
        int arow = mf * 16 + l16;
        bf16x8 af = *(const bf16x8*)(As + (size_t)(arow * 8 + ((ks * 4 + quad) ^ (arow & 7))) * 8);
        acc[mf] = __builtin_amdgcn_mfma_f32_16x16x32_bf16(af, bfr, acc[mf], 0, 0, 0);
      }
    }
    __syncthreads();
  }
#pragma unroll
  for (int mf = 0; mf < 4; mf++) {
#pragma unroll
    for (int r = 0; r < 4; r++) {
      int row = mf * 16 + quad * 4 + r;
      int col = n0 + wave * 16 + l16;
      basep[((size_t)kz * 64 + row) * DIM + col] = acc[mf][r];
    }
  }
}

// ---------------- K6: MetaNet: coefs = relu((Σ_z basep + b2)@mw1+mb1)@mw2 + mb2 ------------
__global__ void k_metanet(const float* __restrict__ basep,  // [4][64][768]
                          const float* __restrict__ b2,
                          const float* __restrict__ mw1, const float* __restrict__ mb1,
                          const float* __restrict__ mw2, const float* __restrict__ mb2,
                          float* __restrict__ coefs) {      // [64][8]
  __shared__ float bl[DIM];
  __shared__ float hl[192];
  int b = blockIdx.x, tid = threadIdx.x;   // 192 threads
  const size_t ZS = (size_t)64 * DIM;
  for (int i = tid; i < DIM; i += 192) {
    size_t o = (size_t)b * DIM + i;
    bl[i] = basep[o] + basep[ZS + o] + basep[2 * ZS + o] + basep[3 * ZS + o] + b2[i];
  }
  __syncthreads();
  float s = mb1[tid];
  for (int k = 0; k < DIM; k++) s += bl[k] * mw1[(size_t)k * 192 + tid];
  hl[tid] = fmaxf(s, 0.0f);
  __syncthreads();
  if (tid < NT) {
    float c = mb2[tid];
    for (int j = 0; j < 192; j++) c += hl[j] * mw2[(size_t)j * NT + tid];
    coefs[b * NT + tid] = c;
  }
}

// ---------------- K5c: fused second GEMM + combine, K-split x4 ----------------
// grid (12 n-tiles, 4 kz). Per block: stage A k-tile once, loop 9 mats
// (W2T + dW2T[8]) over it with reg-pipelined B (issue m+1 before MFMA m,
// 1 barrier/mat). acc[9][4] in VGPRs; epilogue applies coefs weighting:
// Yp[kz][row][col] = acc0 + sum_t cl[row][t]*acc[1+t].
__global__ __launch_bounds__(256)
void k_gemm2c(const float* __restrict__ Af,      // [64][768] f32 (pooledB)
              const bf16* __restrict__ WT,       // mats 9..17 = W2T, dW2T[8]
              const float* __restrict__ coefs,   // [64][8]
              float* __restrict__ Yp) {          // [4][64][768]
  __shared__ uint4 AslU[64 * 8];   // 8KB
  __shared__ uint4 BslU[2][64 * 8];// 16KB
  __shared__ float cl[64][8];
  int n0  = blockIdx.x * 64;
  int kz  = blockIdx.y;
  int tid = threadIdx.x, wave = tid >> 6, lane = tid & 63;
  int quad = lane >> 4, l16 = lane & 15;

  ((float*)cl)[tid]       = coefs[tid];
  ((float*)cl)[256 + tid] = coefs[256 + tid];

  // this thread's two B granules: g0 = tid, g1 = tid+256
  int r0 = tid >> 3,         c0 = tid & 7;
  int r1 = (tid + 256) >> 3, c1 = (tid + 256) & 7;
  int bs0 = r0 * 8 + (c0 ^ (r0 & 7));
  int bs1 = r1 * 8 + (c1 ^ (r1 & 7));

  f32x4 acc[9][4] = {};

  for (int kt = 0; kt < 3; kt++) {
    int k0 = kz * 192 + kt * 64;
    // ---- stage A (f32 -> bf16, swizzled)
#pragma unroll
    for (int i = 0; i < 2; i++) {
      int g = tid + i * 256;
      int r = g >> 3, c = g & 7;
      const float* src = Af + (size_t)r * DIM + k0 + c * 8;
      float4 xa = ((const float4*)src)[0];
      float4 xb = ((const float4*)src)[1];
      BF8 o;
      o.h[0] = __float2bfloat16(xa.x); o.h[1] = __float2bfloat16(xa.y);
      o.h[2] = __float2bfloat16(xa.z); o.h[3] = __float2bfloat16(xa.w);
      o.h[4] = __float2bfloat16(xb.x); o.h[5] = __float2bfloat16(xb.y);
      o.h[6] = __float2bfloat16(xb.z); o.h[7] = __float2bfloat16(xb.w);
      AslU[r * 8 + (c ^ (r & 7))] = *(uint4*)&o;
    }
    // ---- issue mat-0 B loads
    const bf16* W0 = WT + (size_t)9 * MSZ + k0;
    uint4 rcur0 = *(const uint4*)(W0 + (size_t)(n0 + r0) * DIM + c0 * 8);
    uint4 rcur1 = *(const uint4*)(W0 + (size_t)(n0 + r1) * DIM + c1 * 8);
    __syncthreads();   // A visible; prev k-tile's last MFMA reads done
    // ---- A fragments to registers (reused across all 9 mats)
    const bf16* As = (const bf16*)AslU;
    bf16x8 af[2][4];
#pragma unroll
    for (int ks = 0; ks < 2; ks++)
#pragma unroll
      for (int mf = 0; mf < 4; mf++) {
        int arow = mf * 16 + l16;
        af[ks][mf] = *(const bf16x8*)(As + (size_t)(arow * 8 + ((ks * 4 + quad) ^ (arow & 7))) * 8);
      }
    // ---- 9 mats, reg-pipelined B, 1 barrier per mat
#pragma unroll
    for (int m = 0; m < 9; m++) {
      uint4 rnxt0, rnxt1;
      if (m < 8) {
        const bf16* Wn = WT + (size_t)(10 + m) * MSZ + k0;
        rnxt0 = *(const uint4*)(Wn + (size_t)(n0 + r0) * DIM + c0 * 8);
        rnxt1 = *(const uint4*)(Wn + (size_t)(n0 + r1) * DIM + c1 * 8);
      }
      BslU[m & 1][bs0] = rcur0;
      BslU[m & 1][bs1] = rcur1;
      __syncthreads();   // B visible; buf last read at mat m-2 (done pre-barrier)
      const bf16* Bs = (const bf16*)&BslU[m & 1][0];
#pragma unroll
      for (int ks = 0; ks < 2; ks++) {
        int brow = wave * 16 + l16;
        bf16x8 bfr = *(const bf16x8*)(Bs + (size_t)(brow * 8 + ((ks * 4 + quad) ^ (brow & 7))) * 8);
#pragma unroll
        for (int mf = 0; mf < 4; mf++)
          acc[m][mf] = __builtin_amdgcn_mfma_f32_16x16x32_bf16(af[ks][mf], bfr, acc[m][mf], 0, 0, 0);
      }
      rcur0 = rnxt0;
      rcur1 = rnxt1;
    }
    __syncthreads();   // last mat's reads done before next k-tile's A/B writes
  }

  // ---- epilogue: combine with coefs weighting
#pragma unroll
  for (int mf = 0; mf < 4; mf++) {
#pragma unroll
    for (int r = 0; r < 4; r++) {
      int row = mf * 16 + quad * 4 + r;
      int col = n0 + wave * 16 + l16;
      float v = acc[0][mf][r];
#pragma unroll
      for (int t = 0; t < NT; t++) v += cl[row][t] * acc[1 + t][mf][r];
      Yp[((size_t)kz * 64 + row) * DIM + col] = v;
    }
  }
}

// ---------------- K7: sum K-partials + biases: out = Σ_kz Yp + b2 + Σ_t c_t db2_t ----------
__global__ void k_sum4(const float* __restrict__ Yp,     // [4][64][768]
                       const float* __restrict__ coefs,
                       const float* __restrict__ b2,
                       const float* __restrict__ db2,
                       float* __restrict__ out) {
  int idx = blockIdx.x * 256 + threadIdx.x;
  int b = idx / DIM, e = idx % DIM;
  const size_t ZS = (size_t)64 * DIM;
  float v = Yp[idx] + Yp[ZS + idx] + Yp[2 * ZS + idx] + Yp[3 * ZS + idx] + b2[e];
#pragma unroll
  for (int t = 0; t < NT; t++)
    v += coefs[b * NT + t] * db2[(size_t)t * DIM + e];
  out[idx] = v;
}

extern "C" void kernel_launch(void* const* d_in, const int* in_sizes, int n_in,
                              void* d_out, int out_size, void* d_ws, size_t ws_size,
                              hipStream_t stream) {
  const float* x   = (const float*)d_in[0];
  const float* W1  = (const float*)d_in[1];
  const float* b1  = (const float*)d_in[2];
  const float* W2  = (const float*)d_in[3];
  const float* b2  = (const float*)d_in[4];
  const float* dW1 = (const float*)d_in[5];
  const float* db1 = (const float*)d_in[6];
  const float* dW2 = (const float*)d_in[7];
  const float* db2 = (const float*)d_in[8];
  const float* mw1 = (const float*)d_in[9];
  const float* mb1 = (const float*)d_in[10];
  const float* mw2 = (const float*)d_in[11];
  const float* mb2 = (const float*)d_in[12];
  float* out = (float*)d_out;
  (void)in_sizes; (void)n_in; (void)out_size; (void)ws_size;

  // workspace layout (bytes) — total ~48.4 MB
  char* ws = (char*)d_ws;
  bf16*  A_bf    = (bf16*) (ws);                 // 25,165,824
  bf16*  WT      = (bf16*) (ws + 25165824);      // 21,233,664 -> 46,399,488
  float* pooledA = (float*)(ws + 46399488);      //    196,608 -> 46,596,096
  float* pooledB = (float*)(ws + 46596096);      //    196,608 -> 46,792,704
  float* coefs   = (float*)(ws + 46792704);      //      2,048 -> 46,794,752
  float* basep   = (float*)(ws + 46794752);      //    786,432 -> 47,581,184
  float* Yp      = (float*)(ws + 47581184);      //    786,432 -> 48,367,616

  k_prep<<<dim3(PREP_PATCH_BLOCKS + PREP_TRANS_BLOCKS), 256, 0, stream>>>(
      x, A_bf, W1, dW1, W2, dW2, WT);
  // phase A
  k_gemm_pool<0><<<dim3(BATCH, DIM / 64), 256, 0, stream>>>(A_bf, WT, b1, db1, nullptr, pooledA);
  k_gemm2_ksplit<<<dim3(DIM / 64, 4), 256, 0, stream>>>(pooledA, WT, basep);
  k_metanet<<<dim3(BATCH), 192, 0, stream>>>(basep, b2, mw1, mb1, mw2, mb2, coefs);
  // phase B (inline mix from L2-resident WT)
  k_gemm_pool<1><<<dim3(BATCH, DIM / 64), 256, 0, stream>>>(A_bf, WT, b1, db1, coefs, pooledB);
  k_gemm2c<<<dim3(DIM / 64, 4), 256, 0, stream>>>(pooledB, WT, coefs, Yp);
  k_sum4<<<dim3((BATCH * DIM) / 256), 256, 0, stream>>>(Yp, coefs, b2, db2, out);
}